// Round 1
// 82.772 us; speedup vs baseline: 1.0588x; 1.0588x over previous
//
#include <hip/hip_runtime.h>

#define IN_FEATURES 4096
#define OUT_FEATURES 11008
#define KO 128            // k-tiles per partition (2048/16)
#define NW 32             // int32 words per trellis block
#define SEG 16            // split-k segments per partition
#define KO_PER_SEG (KO / SEG)  // 8

// One thread owns one output row (tx) of a 16x16 tile, for 4 batch rows.
// Wave = 4 m-tiles x 16 rows, walking the same k columns in lockstep so x
// addresses are wave-uniform (scalar loads). Decode: idx[s] = 9-bit window
// ending at chunk s of the kv=4 bitstream; thread's row tx needs trellis
// words 2tx-1, 2tx, 2tx+1. Word 2tx-1 comes from lane tx-1 via shfl_up
// (it is that lane's wp.y) instead of a redundant global load.
__global__ __launch_bounds__(256, 6) void tcq_kernel(
    const float* __restrict__ inp,       // [4][4096]
    const int* __restrict__ trellis1,    // [688*128][32]
    const int* __restrict__ trellis2,    // [688*128][32]
    const float* __restrict__ tlut,      // [512][2]
    float* __restrict__ out)             // [4][11008], pre-zeroed
{
    __shared__ float lut[1024];
    {
        const float4* src = reinterpret_cast<const float4*>(tlut);
        float4* dst = reinterpret_cast<float4*>(lut);
        dst[threadIdx.x] = src[threadIdx.x];  // 256 * 16B = 4KB
    }
    __syncthreads();

    const int tid  = threadIdx.x;
    const int lane = tid & 63;
    const int wid  = tid >> 6;
    const int tx   = lane & 15;          // row within tile
    const int mt   = lane >> 4;          // m-tile within wave (0..3)
    const int mo   = blockIdx.x * 16 + wid * 4 + mt;   // global m-tile (0..687)
    const int m    = mo * 16 + tx;       // output row
    const int ko0  = blockIdx.y * KO_PER_SEG;
    const int part = blockIdx.z;

    const int* __restrict__ tre =
        (part ? trellis2 : trellis1) + (mo * KO + ko0) * NW;
    const float* __restrict__ xbase = inp + part * 2048 + ko0 * 16;

    // even-k and odd-k partial sums per batch (8 independent FMA chains)
    float accE[4] = {0.f, 0.f, 0.f, 0.f};
    float accO[4] = {0.f, 0.f, 0.f, 0.f};

    // software pipeline: trellis words for kk+1 load while kk computes
    int2 wp = *reinterpret_cast<const int2*>(tre + 2 * tx);

    #pragma unroll
    for (int kk = 0; kk < KO_PER_SEG; ++kk) {
        const int2 wpc = wp;
        if (kk + 1 < KO_PER_SEG)
            wp = *reinterpret_cast<const int2*>(tre + (kk + 1) * NW + 2 * tx);

        // word 2tx-1 from neighbor lane; state starts 0 per block -> 0 for tx==0
        int wm1 = __shfl_up(wpc.y, 1, 16);
        if (tx == 0) wm1 = 0;

        unsigned comb0 = (unsigned(wm1)   << 16) | (unsigned(wpc.x) & 0xFFFFu);
        unsigned comb1 = (unsigned(wpc.x) << 16) | (unsigned(wpc.y) & 0xFFFFu);

        // x for this tile: 16 consecutive k values for 4 batch rows.
        // Address is wave-uniform -> compiler emits scalar loads.
        const float* xt = xbase + kk * 16;
        float xs[4][16];
        #pragma unroll
        for (int b = 0; b < 4; ++b) {
            const float4* xv = reinterpret_cast<const float4*>(xt + b * IN_FEATURES);
            #pragma unroll
            for (int q = 0; q < 4; ++q) {
                float4 v = xv[q];
                xs[b][q * 4 + 0] = v.x;
                xs[b][q * 4 + 1] = v.y;
                xs[b][q * 4 + 2] = v.z;
                xs[b][q * 4 + 3] = v.w;
            }
        }

        #pragma unroll
        for (int j = 0; j < 8; ++j) {
            unsigned comb = (j < 4) ? comb0 : comb1;
            const int shift = 12 - 4 * (j & 3);
            unsigned idx = (comb >> shift) & 0x1FFu;
            float w0 = lut[idx * 2];       // -> ds_read_b64
            float w1 = lut[idx * 2 + 1];
            #pragma unroll
            for (int b = 0; b < 4; ++b) {
                accE[b] = fmaf(w0, xs[b][2 * j],     accE[b]);
                accO[b] = fmaf(w1, xs[b][2 * j + 1], accO[b]);
            }
        }
    }

    #pragma unroll
    for (int b = 0; b < 4; ++b) {
        atomicAdd(&out[b * OUT_FEATURES + m], accE[b] + accO[b]);
    }
}

extern "C" void kernel_launch(void* const* d_in, const int* in_sizes, int n_in,
                              void* d_out, int out_size, void* d_ws, size_t ws_size,
                              hipStream_t stream) {
    const float* inp  = (const float*)d_in[0];
    const int*   t1   = (const int*)d_in[1];
    const int*   t2   = (const int*)d_in[2];
    const float* tlut = (const float*)d_in[3];
    float* out = (float*)d_out;

    hipMemsetAsync(out, 0, (size_t)out_size * sizeof(float), stream);

    dim3 grid(43, SEG, 2);   // 43 groups of 16 m-tiles, 16 k-segments, 2 partitions
    dim3 block(256);
    hipLaunchKernelGGL(tcq_kernel, grid, block, 0, stream,
                       inp, t1, t2, tlut, out);
}